// Round 3
// baseline (1214.572 us; speedup 1.0000x reference)
//
#include <hip/hip_runtime.h>
#include <math.h>

#define TINYF 1.17549435e-38f
#define NCHUNK 16
#define CHUNKJ 3125
#define JTILE 256

// ---------------- threefry2x32, key = (0, 42) ----------------
__device__ __forceinline__ unsigned rotl32(unsigned x, int r) {
  return (x << r) | (x >> (32 - r));
}

// partitionable threefry random_bits, 32-bit: counter (0, l), output o0 ^ o1
__device__ __forceinline__ unsigned tf2x32_xor(unsigned x0, unsigned x1) {
  const unsigned k0 = 0u, k1 = 42u, k2 = 0x1BD11BF0u;  // 0x1BD11BDA ^ 0 ^ 42
  x0 += k0; x1 += k1;
#define TFR(r) { x0 += x1; x1 = rotl32(x1, r); x1 ^= x0; }
  TFR(13) TFR(15) TFR(26) TFR(6)
  x0 += k1; x1 += k2 + 1u;
  TFR(17) TFR(29) TFR(16) TFR(24)
  x0 += k2; x1 += k0 + 2u;
  TFR(13) TFR(15) TFR(26) TFR(6)
  x0 += k0; x1 += k1 + 3u;
  TFR(17) TFR(29) TFR(16) TFR(24)
  x0 += k1; x1 += k2 + 4u;
  TFR(13) TFR(15) TFR(26) TFR(6)
  x0 += k2; x1 += k0 + 5u;
#undef TFR
  return x0 ^ x1;
}

__device__ __forceinline__ float gumbel_from_bits(unsigned bits) {
  float f = __uint_as_float((bits >> 9) | 0x3f800000u) - 1.0f;
  float u = fmaxf(f, TINYF);  // == max(tiny, f*(1-tiny)+tiny) in f32
  return -logf(-logf(u));
}

// ---------------- h = x @ W + b (f64 accumulate) ----------------
__global__ void k_hraw(const float* __restrict__ x, const float* __restrict__ W,
                       const float* __restrict__ b, float* __restrict__ hraw) {
  __shared__ float sx[256];
  const int i = blockIdx.x;
  const int d = threadIdx.x;  // 128 threads
  sx[d] = x[i * 256 + d];
  sx[d + 128] = x[i * 256 + 128 + d];
  __syncthreads();
  double acc = 0.0;
  for (int k = 0; k < 256; ++k)
    acc = fma((double)sx[k], (double)W[k * 128 + d], acc);
  hraw[i * 128 + d] = (float)acc + b[d];
}

// ---------------- BN stats per column (f64) ----------------
__global__ void k_bnstats(const float* __restrict__ hraw,
                          float* __restrict__ meanv, float* __restrict__ rsv) {
  __shared__ double red[256];
  const int d = blockIdx.x;   // 128 blocks
  const int t = threadIdx.x;  // 256 threads
  double s = 0.0;
  for (int i = t; i < 2048; i += 256) s += (double)hraw[i * 128 + d];
  red[t] = s;
  __syncthreads();
  for (int off = 128; off > 0; off >>= 1) {
    if (t < off) red[t] += red[t + off];
    __syncthreads();
  }
  const float m = (float)(red[0] * (1.0 / 2048.0));
  __syncthreads();
  double v = 0.0;
  for (int i = t; i < 2048; i += 256) {
    float dd = __fsub_rn(hraw[i * 128 + d], m);
    v += (double)dd * (double)dd;
  }
  red[t] = v;
  __syncthreads();
  for (int off = 128; off > 0; off >>= 1) {
    if (t < off) red[t] += red[t + off];
    __syncthreads();
  }
  if (t == 0) {
    float var = (float)(red[0] * (1.0 / 2048.0));
    float vpe = __fadd_rn(var, 1e-5f);
    meanv[d] = m;
    rsv[d] = (float)(1.0 / sqrt((double)vpe));
  }
}

// ---------------- apply BN + leaky relu ----------------
__global__ void k_apply(const float* __restrict__ hraw,
                        const float* __restrict__ meanv, const float* __restrict__ rsv,
                        const float* __restrict__ gamma, const float* __restrict__ beta,
                        float* __restrict__ hfin) {
  const int idx = blockIdx.x * 256 + threadIdx.x;  // 1024 blocks x 256
  const int d = idx & 127;
  float h = hraw[idx];
  float hn = __fadd_rn(__fmul_rn(__fmul_rn(__fsub_rn(h, meanv[d]), rsv[d]), gamma[d]), beta[d]);
  hfin[idx] = (hn >= 0.0f) ? hn : __fmul_rn(0.01f, hn);
}

// ---------------- fused scores + gumbel + argmax ----------------
// grid 2048: bid = rowtile*16 + chunk; rowtile in [0,128) -> rows
// r0 = rowtile*16 .. r0+15; chunk c in [0,16) -> j in [c*3125,(c+1)*3125).
// bid%8 == c%8 -> each XCD's L2 keeps its 2 chunks of all_items resident.
__global__ __launch_bounds__(256) void k_scores(const float* __restrict__ hfin,
                                                const float* __restrict__ items,
                                                float* __restrict__ pmax,
                                                int* __restrict__ pidx) {
  __shared__ __align__(16) float sh_a[256 * 33];  // 256 j x 32 k, stride 33
  __shared__ __align__(16) float sh_h[2048];      // 16 rows x 128
  const int t = threadIdx.x;
  const int bid = blockIdx.x;
  const int rowtile = bid >> 4;
  const int c = bid & 15;
  const int r0 = rowtile * 16;
  const int jlo = c * CHUNKJ;
  const int jhi = jlo + CHUNKJ;

  for (int q = 0; q < 8; ++q) {
    int f = q * 256 + t;
    int p = f >> 7;
    int k = f & 127;
    sh_h[f] = hfin[(r0 + p) * 128 + k];
  }

  float vmax[16];
  int vidx[16];
#pragma unroll
  for (int p = 0; p < 16; ++p) { vmax[p] = -INFINITY; vidx[p] = 0; }

  for (int jt = jlo; jt < jhi; jt += JTILE) {
    float vacc[16];
#pragma unroll
    for (int p = 0; p < 16; ++p) vacc[p] = 0.0f;

    for (int ks = 0; ks < 4; ++ks) {
      const int k0 = ks * 32;
      __syncthreads();  // previous slice fully consumed
#pragma unroll
      for (int q = 0; q < 8; ++q) {
        int fidx = q * 256 + t;   // float4 id
        int jrow = fidx >> 3;
        int kq = fidx & 7;
        int j = jt + jrow;
        float4 v = make_float4(0.0f, 0.0f, 0.0f, 0.0f);
        if (j < jhi)
          v = *(const float4*)(items + (size_t)j * 128 + k0 + kq * 4);
        float* dst = &sh_a[jrow * 33 + kq * 4];
        dst[0] = v.x; dst[1] = v.y; dst[2] = v.z; dst[3] = v.w;
      }
      __syncthreads();

      float areg[32];
#pragma unroll
      for (int k = 0; k < 32; ++k) areg[k] = sh_a[t * 33 + k];

#pragma unroll
      for (int p = 0; p < 16; ++p) {
        const float* hp = &sh_h[p * 128 + k0];
        float acc = vacc[p];
#pragma unroll
        for (int i = 0; i < 8; ++i) {
          float4 hv = *(const float4*)(hp + i * 4);  // broadcast read
          acc += hv.x * areg[4 * i + 0];
          acc += hv.y * areg[4 * i + 1];
          acc += hv.z * areg[4 * i + 2];
          acc += hv.w * areg[4 * i + 3];
        }
        vacc[p] = acc;
      }
    }

    // epilogue: partitionable-threefry gumbel + running argmax (j = jt + t)
    const int j = jt + t;
    const bool valid = j < jhi;
#pragma unroll
    for (int p = 0; p < 16; ++p) {
      unsigned l = (unsigned)(r0 + p) * 50000u + (unsigned)j;
      unsigned bb = tf2x32_xor(0u, l);
      float s = vacc[p] + gumbel_from_bits(bb);
      if (valid && s > vmax[p]) { vmax[p] = s; vidx[p] = j; }
    }
  }

  // block-level merge (first-index tie rule)
  __syncthreads();
  float* rm = sh_a;
  int* ri = (int*)(sh_a + 4096);
#pragma unroll
  for (int p = 0; p < 16; ++p) { rm[p * 256 + t] = vmax[p]; ri[p * 256 + t] = vidx[p]; }
  __syncthreads();
  for (int off = 128; off >= 1; off >>= 1) {
    if (t < off) {
      for (int p = 0; p < 16; ++p) {
        float a = rm[p * 256 + t], bb = rm[p * 256 + t + off];
        int ia = ri[p * 256 + t], ib = ri[p * 256 + t + off];
        if (bb > a || (bb == a && ib < ia)) { rm[p * 256 + t] = bb; ri[p * 256 + t] = ib; }
      }
    }
    __syncthreads();
  }
  if (t < 16) {
    pmax[(r0 + t) * NCHUNK + c] = rm[t * 256];
    pidx[(r0 + t) * NCHUNK + c] = ri[t * 256];
  }
}

// ---------------- chunk merge + cosine sim (one wave per row) ----------------
__global__ void k_final(const float* __restrict__ pmax, const int* __restrict__ pidx,
                        const int* __restrict__ uid, const float* __restrict__ items,
                        float* __restrict__ dout, float* __restrict__ simv) {
  const int r = blockIdx.x;
  const int lane = threadIdx.x;  // 64
  float bm = -INFINITY;
  int bi = 0;
  for (int c = 0; c < NCHUNK; ++c) {  // ascending c = ascending j
    float v = pmax[r * NCHUNK + c];
    int id = pidx[r * NCHUNK + c];
    if (v > bm || (v == bm && id < bi)) { bm = v; bi = id; }
  }
  if (lane == 0) dout[r] = (float)bi;

  const int orig = uid[r * 2 + 1];
  float o1 = items[(size_t)orig * 128 + lane];
  float o2 = items[(size_t)orig * 128 + 64 + lane];
  float p1 = items[(size_t)bi * 128 + lane];
  float p2 = items[(size_t)bi * 128 + 64 + lane];
  float d = o1 * p1 + o2 * p2;
  float s1 = o1 * o1 + o2 * o2;
  float s2 = p1 * p1 + p2 * p2;
  for (int off = 32; off > 0; off >>= 1) {
    d += __shfl_down(d, off);
    s1 += __shfl_down(s1, off);
    s2 += __shfl_down(s2, off);
  }
  if (lane == 0) {
    float n1 = fmaxf(sqrtf(s1), 1e-6f);
    float n2 = fmaxf(sqrtf(s2), 1e-6f);
    float sim = d / (n1 * n2);
    simv[r] = (sim + 1.0f) * 0.5f;
  }
}

// ---------------- final scalar reductions ----------------
__global__ void k_reduce(const float* __restrict__ simv, float* __restrict__ dout) {
  __shared__ double rl[256];
  __shared__ double rs[256];
  const int t = threadIdx.x;
  double L = 0.0, S = 0.0;
  for (int i = t; i < 2048; i += 256) {
    double s = (double)simv[i];
    double dd = s - 0.5;
    L += dd * dd;
    S += s;
  }
  rl[t] = L; rs[t] = S;
  __syncthreads();
  for (int off = 128; off > 0; off >>= 1) {
    if (t < off) { rl[t] += rl[t + off]; rs[t] += rs[t + off]; }
    __syncthreads();
  }
  if (t == 0) {
    dout[2048] = (float)(rl[0] * (1.0 / 2048.0));
    dout[2049] = (float)(rs[0] * (1.0 / 2048.0));
  }
}

extern "C" void kernel_launch(void* const* d_in, const int* in_sizes, int n_in,
                              void* d_out, int out_size, void* d_ws, size_t ws_size,
                              hipStream_t stream) {
  const int* uid = (const int*)d_in[0];       // (2048,2) int32
  const float* xfeat = (const float*)d_in[1]; // (2048,256)
  const float* items = (const float*)d_in[2]; // (50000,128)
  const float* W = (const float*)d_in[3];     // (256,128)
  const float* bias = (const float*)d_in[4];  // (128,)
  const float* gamma = (const float*)d_in[5]; // (128,)
  const float* beta = (const float*)d_in[6];  // (128,)

  float* ws = (float*)d_ws;
  float* hraw = ws;                  // 262144
  float* hfin = ws + 262144;         // 262144
  float* meanv = ws + 524288;        // 128
  float* rsv = ws + 524416;          // 128
  float* pmax = ws + 524544;         // 2048*16
  int* pidx = (int*)(ws + 557312);   // 2048*16
  float* simv = ws + 590080;         // 2048
  float* dout = (float*)d_out;       // 2050 floats

  hipLaunchKernelGGL(k_hraw, dim3(2048), dim3(128), 0, stream, xfeat, W, bias, hraw);
  hipLaunchKernelGGL(k_bnstats, dim3(128), dim3(256), 0, stream, hraw, meanv, rsv);
  hipLaunchKernelGGL(k_apply, dim3(1024), dim3(256), 0, stream, hraw, meanv, rsv, gamma, beta, hfin);
  hipLaunchKernelGGL(k_scores, dim3(2048), dim3(256), 0, stream, hfin, items, pmax, pidx);
  hipLaunchKernelGGL(k_final, dim3(2048), dim3(64), 0, stream, pmax, pidx, uid, items, dout, simv);
  hipLaunchKernelGGL(k_reduce, dim3(1), dim3(256), 0, stream, simv, dout);
}

// Round 4
// 1078.674 us; speedup vs baseline: 1.1260x; 1.1260x over previous
//
#include <hip/hip_runtime.h>
#include <math.h>

#define TINYF 1.17549435e-38f
#define NCHUNK 16
#define CHUNKJ 3125
#define JTILE 512
#define QCAP 2048
#define GMAX 16.0f   // hard upper bound on gumbel (15.9424) + slack

// ---------------- threefry2x32, key = (0, 42), partitionable xor-combine ----
__device__ __forceinline__ unsigned rotl32(unsigned x, int r) {
  return (x << r) | (x >> (32 - r));
}

__device__ __forceinline__ unsigned tf2x32_xor(unsigned x0, unsigned x1) {
  const unsigned k0 = 0u, k1 = 42u, k2 = 0x1BD11BF0u;  // 0x1BD11BDA ^ 0 ^ 42
  x0 += k0; x1 += k1;
#define TFR(r) { x0 += x1; x1 = rotl32(x1, r); x1 ^= x0; }
  TFR(13) TFR(15) TFR(26) TFR(6)
  x0 += k1; x1 += k2 + 1u;
  TFR(17) TFR(29) TFR(16) TFR(24)
  x0 += k2; x1 += k0 + 2u;
  TFR(13) TFR(15) TFR(26) TFR(6)
  x0 += k0; x1 += k1 + 3u;
  TFR(17) TFR(29) TFR(16) TFR(24)
  x0 += k1; x1 += k2 + 4u;
  TFR(13) TFR(15) TFR(26) TFR(6)
  x0 += k2; x1 += k0 + 5u;
#undef TFR
  return x0 ^ x1;
}

__device__ __forceinline__ float gumbel_from_bits(unsigned bits) {
  float f = __uint_as_float((bits >> 9) | 0x3f800000u) - 1.0f;
  float u = fmaxf(f, TINYF);
  return -logf(-logf(u));
}

// order-preserving float->uint (monotone)
__device__ __forceinline__ unsigned ordf(float v) {
  unsigned b = __float_as_uint(v);
  return (b & 0x80000000u) ? ~b : (b | 0x80000000u);
}
__device__ __forceinline__ float unordf(unsigned u) {
  unsigned b = (u & 0x80000000u) ? (u & 0x7FFFFFFFu) : ~u;
  return __uint_as_float(b);
}

// ---------------- h = x @ W + b (f64 accumulate) ----------------
__global__ void k_hraw(const float* __restrict__ x, const float* __restrict__ W,
                       const float* __restrict__ b, float* __restrict__ hraw) {
  __shared__ float sx[256];
  const int i = blockIdx.x;
  const int d = threadIdx.x;  // 128 threads
  sx[d] = x[i * 256 + d];
  sx[d + 128] = x[i * 256 + 128 + d];
  __syncthreads();
  double acc = 0.0;
  for (int k = 0; k < 256; ++k)
    acc = fma((double)sx[k], (double)W[k * 128 + d], acc);
  hraw[i * 128 + d] = (float)acc + b[d];
}

// ---------------- BN stats per column (f64) ----------------
__global__ void k_bnstats(const float* __restrict__ hraw,
                          float* __restrict__ meanv, float* __restrict__ rsv) {
  __shared__ double red[256];
  const int d = blockIdx.x;   // 128 blocks
  const int t = threadIdx.x;  // 256 threads
  double s = 0.0;
  for (int i = t; i < 2048; i += 256) s += (double)hraw[i * 128 + d];
  red[t] = s;
  __syncthreads();
  for (int off = 128; off > 0; off >>= 1) {
    if (t < off) red[t] += red[t + off];
    __syncthreads();
  }
  const float m = (float)(red[0] * (1.0 / 2048.0));
  __syncthreads();
  double v = 0.0;
  for (int i = t; i < 2048; i += 256) {
    float dd = __fsub_rn(hraw[i * 128 + d], m);
    v += (double)dd * (double)dd;
  }
  red[t] = v;
  __syncthreads();
  for (int off = 128; off > 0; off >>= 1) {
    if (t < off) red[t] += red[t + off];
    __syncthreads();
  }
  if (t == 0) {
    float var = (float)(red[0] * (1.0 / 2048.0));
    float vpe = __fadd_rn(var, 1e-5f);
    meanv[d] = m;
    rsv[d] = (float)(1.0 / sqrt((double)vpe));
  }
}

// ---------------- apply BN + leaky relu ----------------
__global__ void k_apply(const float* __restrict__ hraw,
                        const float* __restrict__ meanv, const float* __restrict__ rsv,
                        const float* __restrict__ gamma, const float* __restrict__ beta,
                        float* __restrict__ hfin) {
  const int idx = blockIdx.x * 256 + threadIdx.x;
  const int d = idx & 127;
  float h = hraw[idx];
  float hn = __fadd_rn(__fmul_rn(__fmul_rn(__fsub_rn(h, meanv[d]), rsv[d]), gamma[d]), beta[d]);
  hfin[idx] = (hn >= 0.0f) ? hn : __fmul_rn(0.01f, hn);
}

// ---------------- V0 seed: per-row achieved max over j in [0,1024) ----------
// 512 blocks x 256 threads; block handles rows 4b..4b+3.
__global__ __launch_bounds__(256) void k_seed(const float* __restrict__ hfin,
                                              const float* __restrict__ items,
                                              float* __restrict__ V0) {
  __shared__ float red[4][256];
  const int t = threadIdx.x;
  const int rbase = blockIdx.x * 4;
  float best[4] = {-INFINITY, -INFINITY, -INFINITY, -INFINITY};
  for (int q = 0; q < 4; ++q) {
    const int j = t + 256 * q;
    float acc[4] = {0.0f, 0.0f, 0.0f, 0.0f};
    const float* ap = items + (size_t)j * 128;
    for (int km = 0; km < 8; ++km) {
      float4 a4[4];
#pragma unroll
      for (int e = 0; e < 4; ++e) a4[e] = *(const float4*)(ap + km * 16 + 4 * e);
#pragma unroll
      for (int p = 0; p < 4; ++p) {
        const float* hp = hfin + (rbase + p) * 128 + km * 16;  // uniform -> s_load
#pragma unroll
        for (int e = 0; e < 4; ++e) {
          float4 h4 = *(const float4*)(hp + 4 * e);
          acc[p] = fmaf(h4.x, a4[e].x, acc[p]);
          acc[p] = fmaf(h4.y, a4[e].y, acc[p]);
          acc[p] = fmaf(h4.z, a4[e].z, acc[p]);
          acc[p] = fmaf(h4.w, a4[e].w, acc[p]);
        }
      }
    }
#pragma unroll
    for (int p = 0; p < 4; ++p) {
      unsigned l = (unsigned)(rbase + p) * 50000u + (unsigned)j;
      float g = gumbel_from_bits(tf2x32_xor(0u, l));
      best[p] = fmaxf(best[p], acc[p] + g);
    }
  }
#pragma unroll
  for (int p = 0; p < 4; ++p) red[p][t] = best[p];
  __syncthreads();
  for (int off = 128; off > 0; off >>= 1) {
    if (t < off) {
#pragma unroll
      for (int p = 0; p < 4; ++p) red[p][t] = fmaxf(red[p][t], red[p][t + off]);
    }
    __syncthreads();
  }
  if (t < 4) V0[rbase + t] = red[t][0];
}

// ---------------- fused scores + pruned gumbel + argmax ----------------
// grid 2048: bid = rowtile*16 + chunk; rows r0..r0+15, j in [c*3125,(c+1)*3125).
// No LDS in the hot loop: a from L2 (float4), h via wave-uniform scalar loads.
// Candidates (s + GMAX >= V0) compacted to an LDS queue, processed densely.
__global__ __launch_bounds__(256) void k_scores(const float* __restrict__ hfin,
                                                const float* __restrict__ items,
                                                const float* __restrict__ V0,
                                                float* __restrict__ pmax,
                                                int* __restrict__ pidx) {
  __shared__ unsigned q_key[QCAP];
  __shared__ float q_val[QCAP];
  __shared__ unsigned long long rowslot[16];
  __shared__ unsigned q_cnt;

  const int t = threadIdx.x;
  const int bid = blockIdx.x;
  const int rowtile = bid >> 4;
  const int c = bid & 15;
  const int r0 = rowtile * 16;
  const int jlo = c * CHUNKJ;
  const int jhi = jlo + CHUNKJ;

  if (t == 0) q_cnt = 0;
  if (t < 16) rowslot[t] = 0ull;
  __syncthreads();

  for (int jt = 0; jt < 7; ++jt) {
    const int jA = jlo + jt * JTILE + t;
    const int jB = jA + 256;
    const bool vA = jA < jhi;
    const bool vB = jB < jhi;
    const int jAc = (jA < 49999) ? jA : 49999;
    const int jBc = (jB < 49999) ? jB : 49999;
    const float* apA = items + (size_t)jAc * 128;
    const float* apB = items + (size_t)jBc * 128;

    float acc0[16], acc1[16];
#pragma unroll
    for (int p = 0; p < 16; ++p) { acc0[p] = 0.0f; acc1[p] = 0.0f; }

    for (int km = 0; km < 8; ++km) {
      float4 a0[4], a1[4];
#pragma unroll
      for (int e = 0; e < 4; ++e) {
        a0[e] = *(const float4*)(apA + km * 16 + 4 * e);
        a1[e] = *(const float4*)(apB + km * 16 + 4 * e);
      }
#pragma unroll
      for (int p = 0; p < 16; ++p) {
        const float* hp = hfin + (r0 + p) * 128 + km * 16;  // uniform -> s_load
#pragma unroll
        for (int e = 0; e < 4; ++e) {
          float4 h4 = *(const float4*)(hp + 4 * e);
          acc0[p] = fmaf(h4.x, a0[e].x, acc0[p]);
          acc0[p] = fmaf(h4.y, a0[e].y, acc0[p]);
          acc0[p] = fmaf(h4.z, a0[e].z, acc0[p]);
          acc0[p] = fmaf(h4.w, a0[e].w, acc0[p]);
          acc1[p] = fmaf(h4.x, a1[e].x, acc1[p]);
          acc1[p] = fmaf(h4.y, a1[e].y, acc1[p]);
          acc1[p] = fmaf(h4.z, a1[e].z, acc1[p]);
          acc1[p] = fmaf(h4.w, a1[e].w, acc1[p]);
        }
      }
    }

    // push candidates: keep iff s + GMAX >= V0[row]  (skip can never drop the
    // winner: skipped value <= s + 15.9424 < V0 <= V_final, strictly)
#pragma unroll
    for (int p = 0; p < 16; ++p) {
      const float vth = V0[r0 + p] - GMAX;  // uniform
      if (vA && acc0[p] >= vth) {
        unsigned slot = atomicAdd(&q_cnt, 1u);
        if (slot < QCAP) {
          q_key[slot] = ((unsigned)p << 16) | (unsigned)jA;
          q_val[slot] = acc0[p];
        } else {  // overflow fallback: inline
          unsigned l = (unsigned)(r0 + p) * 50000u + (unsigned)jA;
          float v = acc0[p] + gumbel_from_bits(tf2x32_xor(0u, l));
          unsigned long long pk =
              ((unsigned long long)ordf(v) << 32) | (0xFFFFFFFFu - (unsigned)jA);
          atomicMax(&rowslot[p], pk);
        }
      }
      if (vB && acc1[p] >= vth) {
        unsigned slot = atomicAdd(&q_cnt, 1u);
        if (slot < QCAP) {
          q_key[slot] = ((unsigned)p << 16) | (unsigned)jB;
          q_val[slot] = acc1[p];
        } else {
          unsigned l = (unsigned)(r0 + p) * 50000u + (unsigned)jB;
          float v = acc1[p] + gumbel_from_bits(tf2x32_xor(0u, l));
          unsigned long long pk =
              ((unsigned long long)ordf(v) << 32) | (0xFFFFFFFFu - (unsigned)jB);
          atomicMax(&rowslot[p], pk);
        }
      }
    }
  }

  __syncthreads();
  // dense flush: compute gumbel only for candidates
  const unsigned n = (q_cnt < QCAP) ? q_cnt : QCAP;
  for (unsigned i = t; i < n; i += 256) {
    unsigned key = q_key[i];
    unsigned p = key >> 16;
    unsigned j = key & 0xFFFFu;
    float s = q_val[i];
    unsigned l = (r0 + p) * 50000u + j;
    float v = s + gumbel_from_bits(tf2x32_xor(0u, l));
    unsigned long long pk = ((unsigned long long)ordf(v) << 32) | (0xFFFFFFFFu - j);
    atomicMax(&rowslot[p], pk);
  }
  __syncthreads();

  if (t < 16) {
    unsigned long long pk = rowslot[t];
    if (pk == 0ull) {
      pmax[(r0 + t) * NCHUNK + c] = -INFINITY;
      pidx[(r0 + t) * NCHUNK + c] = 0;
    } else {
      pmax[(r0 + t) * NCHUNK + c] = unordf((unsigned)(pk >> 32));
      pidx[(r0 + t) * NCHUNK + c] = (int)(0xFFFFFFFFu - (unsigned)pk);
    }
  }
}

// ---------------- chunk merge + cosine sim (one wave per row) ----------------
__global__ void k_final(const float* __restrict__ pmax, const int* __restrict__ pidx,
                        const int* __restrict__ uid, const float* __restrict__ items,
                        float* __restrict__ dout, float* __restrict__ simv) {
  const int r = blockIdx.x;
  const int lane = threadIdx.x;  // 64
  float bm = -INFINITY;
  int bi = 0;
  for (int c = 0; c < NCHUNK; ++c) {
    float v = pmax[r * NCHUNK + c];
    int id = pidx[r * NCHUNK + c];
    if (v > bm || (v == bm && id < bi)) { bm = v; bi = id; }
  }
  if (lane == 0) dout[r] = (float)bi;

  const int orig = uid[r * 2 + 1];
  float o1 = items[(size_t)orig * 128 + lane];
  float o2 = items[(size_t)orig * 128 + 64 + lane];
  float p1 = items[(size_t)bi * 128 + lane];
  float p2 = items[(size_t)bi * 128 + 64 + lane];
  float d = o1 * p1 + o2 * p2;
  float s1 = o1 * o1 + o2 * o2;
  float s2 = p1 * p1 + p2 * p2;
  for (int off = 32; off > 0; off >>= 1) {
    d += __shfl_down(d, off);
    s1 += __shfl_down(s1, off);
    s2 += __shfl_down(s2, off);
  }
  if (lane == 0) {
    float n1 = fmaxf(sqrtf(s1), 1e-6f);
    float n2 = fmaxf(sqrtf(s2), 1e-6f);
    float sim = d / (n1 * n2);
    simv[r] = (sim + 1.0f) * 0.5f;
  }
}

// ---------------- final scalar reductions ----------------
__global__ void k_reduce(const float* __restrict__ simv, float* __restrict__ dout) {
  __shared__ double rl[256];
  __shared__ double rs[256];
  const int t = threadIdx.x;
  double L = 0.0, S = 0.0;
  for (int i = t; i < 2048; i += 256) {
    double s = (double)simv[i];
    double dd = s - 0.5;
    L += dd * dd;
    S += s;
  }
  rl[t] = L; rs[t] = S;
  __syncthreads();
  for (int off = 128; off > 0; off >>= 1) {
    if (t < off) { rl[t] += rl[t + off]; rs[t] += rs[t + off]; }
    __syncthreads();
  }
  if (t == 0) {
    dout[2048] = (float)(rl[0] * (1.0 / 2048.0));
    dout[2049] = (float)(rs[0] * (1.0 / 2048.0));
  }
}

extern "C" void kernel_launch(void* const* d_in, const int* in_sizes, int n_in,
                              void* d_out, int out_size, void* d_ws, size_t ws_size,
                              hipStream_t stream) {
  const int* uid = (const int*)d_in[0];       // (2048,2) int32
  const float* xfeat = (const float*)d_in[1]; // (2048,256)
  const float* items = (const float*)d_in[2]; // (50000,128)
  const float* W = (const float*)d_in[3];     // (256,128)
  const float* bias = (const float*)d_in[4];  // (128,)
  const float* gamma = (const float*)d_in[5]; // (128,)
  const float* beta = (const float*)d_in[6];  // (128,)

  float* ws = (float*)d_ws;
  float* hraw = ws;                  // 262144
  float* hfin = ws + 262144;         // 262144
  float* meanv = ws + 524288;        // 128
  float* rsv = ws + 524416;          // 128
  float* V0 = ws + 524544;           // 2048
  float* pmax = ws + 526592;         // 2048*16
  int* pidx = (int*)(ws + 559360);   // 2048*16
  float* simv = ws + 592128;         // 2048
  float* dout = (float*)d_out;       // 2050 floats

  hipLaunchKernelGGL(k_hraw, dim3(2048), dim3(128), 0, stream, xfeat, W, bias, hraw);
  hipLaunchKernelGGL(k_bnstats, dim3(128), dim3(256), 0, stream, hraw, meanv, rsv);
  hipLaunchKernelGGL(k_apply, dim3(1024), dim3(256), 0, stream, hraw, meanv, rsv, gamma, beta, hfin);
  hipLaunchKernelGGL(k_seed, dim3(512), dim3(256), 0, stream, hfin, items, V0);
  hipLaunchKernelGGL(k_scores, dim3(2048), dim3(256), 0, stream, hfin, items, V0, pmax, pidx);
  hipLaunchKernelGGL(k_final, dim3(2048), dim3(64), 0, stream, pmax, pidx, uid, items, dout, simv);
  hipLaunchKernelGGL(k_reduce, dim3(1), dim3(256), 0, stream, simv, dout);
}

// Round 5
// 1068.724 us; speedup vs baseline: 1.1365x; 1.0093x over previous
//
#include <hip/hip_runtime.h>
#include <math.h>

#define TINYF 1.17549435e-38f
#define NCHUNK 16
#define CHUNKJ 3125
#define JTILE 512
#define QCAP 2048
#define GMAX 16.0f   // hard upper bound on gumbel (15.9424) + slack

// ---------------- threefry2x32, key = (0, 42), partitionable xor-combine ----
__device__ __forceinline__ unsigned rotl32(unsigned x, int r) {
  return (x << r) | (x >> (32 - r));
}

__device__ __forceinline__ unsigned tf2x32_xor(unsigned x0, unsigned x1) {
  const unsigned k0 = 0u, k1 = 42u, k2 = 0x1BD11BF0u;  // 0x1BD11BDA ^ 0 ^ 42
  x0 += k0; x1 += k1;
#define TFR(r) { x0 += x1; x1 = rotl32(x1, r); x1 ^= x0; }
  TFR(13) TFR(15) TFR(26) TFR(6)
  x0 += k1; x1 += k2 + 1u;
  TFR(17) TFR(29) TFR(16) TFR(24)
  x0 += k2; x1 += k0 + 2u;
  TFR(13) TFR(15) TFR(26) TFR(6)
  x0 += k0; x1 += k1 + 3u;
  TFR(17) TFR(29) TFR(16) TFR(24)
  x0 += k1; x1 += k2 + 4u;
  TFR(13) TFR(15) TFR(26) TFR(6)
  x0 += k2; x1 += k0 + 5u;
#undef TFR
  return x0 ^ x1;
}

__device__ __forceinline__ float gumbel_from_bits(unsigned bits) {
  float f = __uint_as_float((bits >> 9) | 0x3f800000u) - 1.0f;
  float u = fmaxf(f, TINYF);
  return -logf(-logf(u));
}

// order-preserving float->uint (monotone)
__device__ __forceinline__ unsigned ordf(float v) {
  unsigned b = __float_as_uint(v);
  return (b & 0x80000000u) ? ~b : (b | 0x80000000u);
}
__device__ __forceinline__ float unordf(unsigned u) {
  unsigned b = (u & 0x80000000u) ? (u & 0x7FFFFFFFu) : ~u;
  return __uint_as_float(b);
}

// ---------------- h = x @ W + b (f64 accumulate) ----------------
__global__ void k_hraw(const float* __restrict__ x, const float* __restrict__ W,
                       const float* __restrict__ b, float* __restrict__ hraw) {
  __shared__ float sx[256];
  const int i = blockIdx.x;
  const int d = threadIdx.x;  // 128 threads
  sx[d] = x[i * 256 + d];
  sx[d + 128] = x[i * 256 + 128 + d];
  __syncthreads();
  double acc = 0.0;
  for (int k = 0; k < 256; ++k)
    acc = fma((double)sx[k], (double)W[k * 128 + d], acc);
  hraw[i * 128 + d] = (float)acc + b[d];
}

// ---------------- BN stats per column (f64) ----------------
__global__ void k_bnstats(const float* __restrict__ hraw,
                          float* __restrict__ meanv, float* __restrict__ rsv) {
  __shared__ double red[256];
  const int d = blockIdx.x;   // 128 blocks
  const int t = threadIdx.x;  // 256 threads
  double s = 0.0;
  for (int i = t; i < 2048; i += 256) s += (double)hraw[i * 128 + d];
  red[t] = s;
  __syncthreads();
  for (int off = 128; off > 0; off >>= 1) {
    if (t < off) red[t] += red[t + off];
    __syncthreads();
  }
  const float m = (float)(red[0] * (1.0 / 2048.0));
  __syncthreads();
  double v = 0.0;
  for (int i = t; i < 2048; i += 256) {
    float dd = __fsub_rn(hraw[i * 128 + d], m);
    v += (double)dd * (double)dd;
  }
  red[t] = v;
  __syncthreads();
  for (int off = 128; off > 0; off >>= 1) {
    if (t < off) red[t] += red[t + off];
    __syncthreads();
  }
  if (t == 0) {
    float var = (float)(red[0] * (1.0 / 2048.0));
    float vpe = __fadd_rn(var, 1e-5f);
    meanv[d] = m;
    rsv[d] = (float)(1.0 / sqrt((double)vpe));
  }
}

// ---------------- apply BN + leaky relu ----------------
__global__ void k_apply(const float* __restrict__ hraw,
                        const float* __restrict__ meanv, const float* __restrict__ rsv,
                        const float* __restrict__ gamma, const float* __restrict__ beta,
                        float* __restrict__ hfin) {
  const int idx = blockIdx.x * 256 + threadIdx.x;
  const int d = idx & 127;
  float h = hraw[idx];
  float hn = __fadd_rn(__fmul_rn(__fmul_rn(__fsub_rn(h, meanv[d]), rsv[d]), gamma[d]), beta[d]);
  hfin[idx] = (hn >= 0.0f) ? hn : __fmul_rn(0.01f, hn);
}

// ---------------- V0 seed: per-row achieved max over j in [0,1024) ----------
__global__ __launch_bounds__(256, 4) void k_seed(const float* __restrict__ hfin,
                                                 const float* __restrict__ items,
                                                 float* __restrict__ V0) {
  __shared__ float red[4][256];
  const int t = threadIdx.x;
  const int rbase = blockIdx.x * 4;
  float best[4] = {-INFINITY, -INFINITY, -INFINITY, -INFINITY};
  for (int q = 0; q < 4; ++q) {
    const int j = t + 256 * q;
    float acc[4] = {0.0f, 0.0f, 0.0f, 0.0f};
    const float* ap = items + (size_t)j * 128;
    for (int km = 0; km < 8; ++km) {
#pragma unroll
      for (int e = 0; e < 4; ++e) {
        float4 a4 = *(const float4*)(ap + km * 16 + 4 * e);
#pragma unroll
        for (int p = 0; p < 4; ++p) {
          const float* hp = hfin + (rbase + p) * 128 + km * 16 + 4 * e;
          float4 h4 = *(const float4*)hp;  // uniform -> s_load
          acc[p] = fmaf(h4.x, a4.x, acc[p]);
          acc[p] = fmaf(h4.y, a4.y, acc[p]);
          acc[p] = fmaf(h4.z, a4.z, acc[p]);
          acc[p] = fmaf(h4.w, a4.w, acc[p]);
        }
      }
    }
#pragma unroll
    for (int p = 0; p < 4; ++p) {
      unsigned l = (unsigned)(rbase + p) * 50000u + (unsigned)j;
      float g = gumbel_from_bits(tf2x32_xor(0u, l));
      best[p] = fmaxf(best[p], acc[p] + g);
    }
  }
#pragma unroll
  for (int p = 0; p < 4; ++p) red[p][t] = best[p];
  __syncthreads();
  for (int off = 128; off > 0; off >>= 1) {
    if (t < off) {
#pragma unroll
      for (int p = 0; p < 4; ++p) red[p][t] = fmaxf(red[p][t], red[p][t + off]);
    }
    __syncthreads();
  }
  if (t < 4) V0[rbase + t] = red[t][0];
}

// ---------------- fused scores + pruned gumbel + argmax ----------------
// grid 2048: bid = rowtile*16 + chunk; rows r0..r0+15, j in [c*3125,(c+1)*3125).
// launch_bounds(256,4): cap 4 waves/EU -> 128 VGPRs so acc0/acc1 stay resident
// (at default the compiler targeted 8 waves/EU = 64 VGPRs and spilled the
// accumulators to scratch -> the round-4 1030us).
__global__ __launch_bounds__(256, 4) void k_scores(const float* __restrict__ hfin,
                                                   const float* __restrict__ items,
                                                   const float* __restrict__ V0,
                                                   float* __restrict__ pmax,
                                                   int* __restrict__ pidx) {
  __shared__ unsigned q_key[QCAP];
  __shared__ float q_val[QCAP];
  __shared__ unsigned long long rowslot[16];
  __shared__ unsigned q_cnt;

  const int t = threadIdx.x;
  const int bid = blockIdx.x;
  const int rowtile = bid >> 4;
  const int c = bid & 15;
  const int r0 = rowtile * 16;
  const int jlo = c * CHUNKJ;
  const int jhi = jlo + CHUNKJ;

  if (t == 0) q_cnt = 0;
  if (t < 16) rowslot[t] = 0ull;
  __syncthreads();

  for (int jt = 0; jt < 7; ++jt) {
    const int jA = jlo + jt * JTILE + t;
    const int jB = jA + 256;
    const bool vA = jA < jhi;
    const bool vB = jB < jhi;
    const int jAc = (jA < 49999) ? jA : 49999;
    const int jBc = (jB < 49999) ? jB : 49999;
    const float* apA = items + (size_t)jAc * 128;
    const float* apB = items + (size_t)jBc * 128;

    float acc0[16], acc1[16];
#pragma unroll
    for (int p = 0; p < 16; ++p) { acc0[p] = 0.0f; acc1[p] = 0.0f; }

    for (int km = 0; km < 8; ++km) {
#pragma unroll
      for (int e = 0; e < 4; ++e) {
        float4 a0 = *(const float4*)(apA + km * 16 + 4 * e);
        float4 a1 = *(const float4*)(apB + km * 16 + 4 * e);
#pragma unroll
        for (int p = 0; p < 16; ++p) {
          const float* hp = hfin + (r0 + p) * 128 + km * 16 + 4 * e;
          float4 h4 = *(const float4*)hp;  // uniform -> s_load
          acc0[p] = fmaf(h4.x, a0.x, acc0[p]);
          acc0[p] = fmaf(h4.y, a0.y, acc0[p]);
          acc0[p] = fmaf(h4.z, a0.z, acc0[p]);
          acc0[p] = fmaf(h4.w, a0.w, acc0[p]);
          acc1[p] = fmaf(h4.x, a1.x, acc1[p]);
          acc1[p] = fmaf(h4.y, a1.y, acc1[p]);
          acc1[p] = fmaf(h4.z, a1.z, acc1[p]);
          acc1[p] = fmaf(h4.w, a1.w, acc1[p]);
        }
      }
    }

    // push candidates: keep iff s + GMAX >= V0[row]
#pragma unroll
    for (int p = 0; p < 16; ++p) {
      const float vth = V0[r0 + p] - GMAX;  // uniform
      if (vA && acc0[p] >= vth) {
        unsigned slot = atomicAdd(&q_cnt, 1u);
        if (slot < QCAP) {
          q_key[slot] = ((unsigned)p << 16) | (unsigned)jA;
          q_val[slot] = acc0[p];
        } else {
          unsigned l = (unsigned)(r0 + p) * 50000u + (unsigned)jA;
          float v = acc0[p] + gumbel_from_bits(tf2x32_xor(0u, l));
          unsigned long long pk =
              ((unsigned long long)ordf(v) << 32) | (0xFFFFFFFFu - (unsigned)jA);
          atomicMax(&rowslot[p], pk);
        }
      }
      if (vB && acc1[p] >= vth) {
        unsigned slot = atomicAdd(&q_cnt, 1u);
        if (slot < QCAP) {
          q_key[slot] = ((unsigned)p << 16) | (unsigned)jB;
          q_val[slot] = acc1[p];
        } else {
          unsigned l = (unsigned)(r0 + p) * 50000u + (unsigned)jB;
          float v = acc1[p] + gumbel_from_bits(tf2x32_xor(0u, l));
          unsigned long long pk =
              ((unsigned long long)ordf(v) << 32) | (0xFFFFFFFFu - (unsigned)jB);
          atomicMax(&rowslot[p], pk);
        }
      }
    }
  }

  __syncthreads();
  // dense flush: compute gumbel only for candidates
  const unsigned n = (q_cnt < QCAP) ? q_cnt : QCAP;
  for (unsigned i = t; i < n; i += 256) {
    unsigned key = q_key[i];
    unsigned p = key >> 16;
    unsigned j = key & 0xFFFFu;
    float s = q_val[i];
    unsigned l = (r0 + p) * 50000u + j;
    float v = s + gumbel_from_bits(tf2x32_xor(0u, l));
    unsigned long long pk = ((unsigned long long)ordf(v) << 32) | (0xFFFFFFFFu - j);
    atomicMax(&rowslot[p], pk);
  }
  __syncthreads();

  if (t < 16) {
    unsigned long long pk = rowslot[t];
    if (pk == 0ull) {
      pmax[(r0 + t) * NCHUNK + c] = -INFINITY;
      pidx[(r0 + t) * NCHUNK + c] = 0;
    } else {
      pmax[(r0 + t) * NCHUNK + c] = unordf((unsigned)(pk >> 32));
      pidx[(r0 + t) * NCHUNK + c] = (int)(0xFFFFFFFFu - (unsigned)pk);
    }
  }
}

// ---------------- chunk merge + cosine sim (one wave per row) ----------------
__global__ void k_final(const float* __restrict__ pmax, const int* __restrict__ pidx,
                        const int* __restrict__ uid, const float* __restrict__ items,
                        float* __restrict__ dout, float* __restrict__ simv) {
  const int r = blockIdx.x;
  const int lane = threadIdx.x;  // 64
  float bm = -INFINITY;
  int bi = 0;
  for (int c = 0; c < NCHUNK; ++c) {
    float v = pmax[r * NCHUNK + c];
    int id = pidx[r * NCHUNK + c];
    if (v > bm || (v == bm && id < bi)) { bm = v; bi = id; }
  }
  if (lane == 0) dout[r] = (float)bi;

  const int orig = uid[r * 2 + 1];
  float o1 = items[(size_t)orig * 128 + lane];
  float o2 = items[(size_t)orig * 128 + 64 + lane];
  float p1 = items[(size_t)bi * 128 + lane];
  float p2 = items[(size_t)bi * 128 + 64 + lane];
  float d = o1 * p1 + o2 * p2;
  float s1 = o1 * o1 + o2 * o2;
  float s2 = p1 * p1 + p2 * p2;
  for (int off = 32; off > 0; off >>= 1) {
    d += __shfl_down(d, off);
    s1 += __shfl_down(s1, off);
    s2 += __shfl_down(s2, off);
  }
  if (lane == 0) {
    float n1 = fmaxf(sqrtf(s1), 1e-6f);
    float n2 = fmaxf(sqrtf(s2), 1e-6f);
    float sim = d / (n1 * n2);
    simv[r] = (sim + 1.0f) * 0.5f;
  }
}

// ---------------- final scalar reductions ----------------
__global__ void k_reduce(const float* __restrict__ simv, float* __restrict__ dout) {
  __shared__ double rl[256];
  __shared__ double rs[256];
  const int t = threadIdx.x;
  double L = 0.0, S = 0.0;
  for (int i = t; i < 2048; i += 256) {
    double s = (double)simv[i];
    double dd = s - 0.5;
    L += dd * dd;
    S += s;
  }
  rl[t] = L; rs[t] = S;
  __syncthreads();
  for (int off = 128; off > 0; off >>= 1) {
    if (t < off) { rl[t] += rl[t + off]; rs[t] += rs[t + off]; }
    __syncthreads();
  }
  if (t == 0) {
    dout[2048] = (float)(rl[0] * (1.0 / 2048.0));
    dout[2049] = (float)(rs[0] * (1.0 / 2048.0));
  }
}

extern "C" void kernel_launch(void* const* d_in, const int* in_sizes, int n_in,
                              void* d_out, int out_size, void* d_ws, size_t ws_size,
                              hipStream_t stream) {
  const int* uid = (const int*)d_in[0];       // (2048,2) int32
  const float* xfeat = (const float*)d_in[1]; // (2048,256)
  const float* items = (const float*)d_in[2]; // (50000,128)
  const float* W = (const float*)d_in[3];     // (256,128)
  const float* bias = (const float*)d_in[4];  // (128,)
  const float* gamma = (const float*)d_in[5]; // (128,)
  const float* beta = (const float*)d_in[6];  // (128,)

  float* ws = (float*)d_ws;
  float* hraw = ws;                  // 262144
  float* hfin = ws + 262144;         // 262144
  float* meanv = ws + 524288;        // 128
  float* rsv = ws + 524416;          // 128
  float* V0 = ws + 524544;           // 2048
  float* pmax = ws + 526592;         // 2048*16
  int* pidx = (int*)(ws + 559360);   // 2048*16
  float* simv = ws + 592128;         // 2048
  float* dout = (float*)d_out;       // 2050 floats

  hipLaunchKernelGGL(k_hraw, dim3(2048), dim3(128), 0, stream, xfeat, W, bias, hraw);
  hipLaunchKernelGGL(k_bnstats, dim3(128), dim3(256), 0, stream, hraw, meanv, rsv);
  hipLaunchKernelGGL(k_apply, dim3(1024), dim3(256), 0, stream, hraw, meanv, rsv, gamma, beta, hfin);
  hipLaunchKernelGGL(k_seed, dim3(512), dim3(256), 0, stream, hfin, items, V0);
  hipLaunchKernelGGL(k_scores, dim3(2048), dim3(256), 0, stream, hfin, items, V0, pmax, pidx);
  hipLaunchKernelGGL(k_final, dim3(2048), dim3(64), 0, stream, pmax, pidx, uid, items, dout, simv);
  hipLaunchKernelGGL(k_reduce, dim3(1), dim3(256), 0, stream, simv, dout);
}